// Round 14
// baseline (105.836 us; speedup 1.0000x reference)
//
#include <hip/hip_runtime.h>

typedef unsigned short u16;
typedef __attribute__((ext_vector_type(8))) __bf16 bf16x8;
typedef __attribute__((ext_vector_type(4))) float f32x4;
typedef __attribute__((ext_vector_type(16))) float f32x16;

#define LOG2E 1.44269504088896f

__device__ __forceinline__ u16 f2bf(float f) {
  union { float f; unsigned u; } c; c.f = f;
  unsigned u = c.u;
  return (u16)((u + 0x7fffu + ((u >> 16) & 1u)) >> 16);
}
__device__ __forceinline__ float bf2f(u16 h) {
  union { unsigned u; float f; } c; c.u = ((unsigned)h) << 16;
  return c.f;
}

__device__ __forceinline__ void load_lds16(const void* g, void* l) {
  __builtin_amdgcn_global_load_lds((const __attribute__((address_space(1))) unsigned int*)g,
                                   (__attribute__((address_space(3))) unsigned int*)l, 16, 0, 0);
}

// ---------------- merged prologue: cast x/enc -> bf16 | trig tables | weight transposes ----------------
__global__ void prologue_kernel(const float* __restrict__ x, const float* __restrict__ enc,
                                const float* __restrict__ freqs,
                                const float* __restrict__ Wq, const float* __restrict__ Wk,
                                const float* __restrict__ Wv, const float* __restrict__ Wo,
                                u16* __restrict__ xb, u16* __restrict__ eb,
                                u16* __restrict__ WqT, u16* __restrict__ WkT,
                                u16* __restrict__ WvT, u16* __restrict__ WoT,
                                float* __restrict__ cstab, float* __restrict__ sntab) {
  __shared__ float tile[32][33];
  int id = blockIdx.x;
  int tid = threadIdx.x;
  if (id < 2048) {
    const int n4each = 1048576;
    int stride = 2048 * 256;
    for (int i = id * 256 + tid; i < 2 * n4each; i += stride) {
      const float4* src; ushort4* dst; int j;
      if (i < n4each) { src = (const float4*)x; dst = (ushort4*)xb; j = i; }
      else            { src = (const float4*)enc; dst = (ushort4*)eb; j = i - n4each; }
      float4 v = src[j];
      ushort4 o;
      o.x = f2bf(v.x); o.y = f2bf(v.y); o.z = f2bf(v.z); o.w = f2bf(v.w);
      dst[j] = o;
    }
    return;
  }
  if (id < 2176) {
    int i = (id - 2048) * 256 + tid;
    float f = freqs[i];
    float sn, cs;
    sincosf(f, &sn, &cs);
    cstab[i] = cs; sntab[i] = sn;
    return;
  }
  int rem = id - 2176;
  int z = rem >> 10;
  int ry = (rem >> 5) & 31;
  int rx = rem & 31;
  const float* in; u16* out; int C;
  if (z == 0)      { in = Wq; out = WqT; C = 1024; }
  else if (z == 1) { in = Wk; out = WkT; C = 512; }
  else if (z == 2) { in = Wv; out = WvT; C = 512; }
  else             { in = Wo; out = WoT; C = 1024; }
  const int R = 1024;
  int c0 = rx * 32, r0 = ry * 32;
  if (c0 >= C) return;
  int tx = tid & 31, ty = tid >> 5;      // (32,8)
#pragma unroll
  for (int i = 0; i < 4; ++i)
    tile[ty + 8 * i][tx] = in[(size_t)(r0 + ty + 8 * i) * C + c0 + tx];
  __syncthreads();
#pragma unroll
  for (int i = 0; i < 4; ++i)
    out[(size_t)(c0 + ty + 8 * i) * R + r0 + tx] = f2bf(tile[tx][ty + 8 * i]);
}

// ---------------- 128x64 bf16 B^T GEMM core (single-buffer 24KB, BK=64, swizzled LDS) ----------------
// Round-13 lesson (m99/m132 regime): explicit dbuf trades occupancy (4->2 blocks/CU) at a net
// loss here; single-buffer + 4 blocks/CU wave-overlap is the faster configuration.
__device__ __forceinline__ void gemm_bn64_core(const u16* A, const u16* Bt, int K,
                                               u16* As, u16* Bs, int m0, int n0,
                                               f32x4 (&acc)[2][4]) {
  int tid = threadIdx.x;
  int w = tid >> 6, l = tid & 63;
  int g = l >> 4, lr = l & 15;
#pragma unroll
  for (int m = 0; m < 2; ++m)
#pragma unroll
    for (int n = 0; n < 4; ++n) acc[m][n] = (f32x4){0.f, 0.f, 0.f, 0.f};

  for (int k0 = 0; k0 < K; k0 += 64) {
#pragma unroll
    for (int rnd = 0; rnd < 4; ++rnd) {
      int bidx = rnd * 4096 + w * 1024 + l * 16;
      int row = bidx >> 7, colb = bidx & 127;
      int scol = colb ^ ((row & 7) << 4);
      load_lds16((const char*)A + ((size_t)(m0 + row) * K + k0) * 2 + scol,
                 (char*)As + rnd * 4096 + w * 1024);
    }
#pragma unroll
    for (int rnd = 0; rnd < 2; ++rnd) {
      int bidx = rnd * 4096 + w * 1024 + l * 16;
      int row = bidx >> 7, colb = bidx & 127;
      int scol = colb ^ ((row & 7) << 4);
      load_lds16((const char*)Bt + ((size_t)(n0 + row) * K + k0) * 2 + scol,
                 (char*)Bs + rnd * 4096 + w * 1024);
    }
    __syncthreads();
    bf16x8 af[2][2], bfr[4][2];
#pragma unroll
    for (int m = 0; m < 2; ++m) {
      int ra = w * 32 + m * 16 + lr;
#pragma unroll
      for (int kf = 0; kf < 2; ++kf)
        af[m][kf] = *(const bf16x8*)((const char*)As + ra * 128 + ((kf * 64 + g * 16) ^ ((ra & 7) << 4)));
    }
#pragma unroll
    for (int n = 0; n < 4; ++n) {
      int rb = n * 16 + lr;
#pragma unroll
      for (int kf = 0; kf < 2; ++kf)
        bfr[n][kf] = *(const bf16x8*)((const char*)Bs + rb * 128 + ((kf * 64 + g * 16) ^ ((rb & 7) << 4)));
    }
#pragma unroll
    for (int m = 0; m < 2; ++m)
#pragma unroll
      for (int n = 0; n < 4; ++n) {
        acc[m][n] = __builtin_amdgcn_mfma_f32_16x16x32_bf16(af[m][0], bfr[n][0], acc[m][n], 0, 0, 0);
        acc[m][n] = __builtin_amdgcn_mfma_f32_16x16x32_bf16(af[m][1], bfr[n][1], acc[m][n], 0, 0, 0);
      }
    __syncthreads();
  }
}

// QKV GEMM (1-D grid, 1536 blocks): id%3==2 -> bias->tiles role, INTERLEAVED in dispatch
// order so bias BW co-runs with GEMM blocks (round-12's tail problem fixed).
// GEMM decode: t=(z,y) fastest so 32 consecutive GEMM blocks share one A panel (L2-local).
__global__ __launch_bounds__(256, 4) void gemm_qkv_kernel(const u16* xb, const u16* eb,
                                                          const u16* WqT, const u16* WkT, const u16* WvT,
                                                          const float* __restrict__ qscale,
                                                          const float* __restrict__ kscale,
                                                          const float* __restrict__ cstab,
                                                          const float* __restrict__ sntab,
                                                          const float* __restrict__ bias,
                                                          u16* Qb, u16* Ktiles, u16* Vtiles,
                                                          u16* __restrict__ biasTT) {
  __shared__ __align__(16) char sh[24576];
  u16* As = (u16*)sh;              // 16 KB
  u16* Bs = (u16*)(sh + 16384);    // 8 KB
  int id = blockIdx.x;
  int sel = id % 3;
  if (sel == 2) {
    // ---- bias->causal-tiles role (512 blocks, woven through dispatch order) ----
    int flat = id / 3;                   // 0..511
    int w = threadIdx.x >> 6, lane = threadIdx.x & 63;
    float* lt = (float*)(sh + w * 4224); // 32x33 floats, wave-private
    int ql = lane & 31, hi = lane >> 5;
    for (int f = flat * 4 + w; f < 8448; f += 2048) {
      int h = f / 528, rem = f - h * 528;
      int qt = (int)((sqrtf(8.f * (float)rem + 1.f) - 1.f) * 0.5f);
      while ((qt + 1) * (qt + 2) / 2 <= rem) ++qt;
      while (qt * (qt + 1) / 2 > rem) --qt;
      int kt = rem - qt * (qt + 1) / 2;
      const float* tsrc = bias + ((size_t)h * 1024 + qt * 32) * 1024 + kt * 32;
#pragma unroll
      for (int i = 0; i < 4; ++i) {
        int row = i * 8 + (lane >> 3);
        int c4 = (lane & 7) * 4;
        float4 v4 = *(const float4*)(tsrc + (size_t)row * 1024 + c4);
        lt[row * 33 + c4 + 0] = v4.x; lt[row * 33 + c4 + 1] = v4.y;
        lt[row * 33 + c4 + 2] = v4.z; lt[row * 33 + c4 + 3] = v4.w;
      }
      u16 v[16];
#pragma unroll
      for (int r = 0; r < 16; ++r) {
        int c = (r & 3) + 8 * (r >> 2) + 4 * hi;
        v[r] = f2bf(lt[ql * 33 + c] * LOG2E);
      }
      u16* dst = biasTT + (size_t)f * 1024 + lane * 16;
#pragma unroll
      for (int i = 0; i < 4; ++i) {
        ushort4 o; o.x = v[i * 4]; o.y = v[i * 4 + 1]; o.z = v[i * 4 + 2]; o.w = v[i * 4 + 3];
        *(ushort4*)(dst + i * 4) = o;
      }
    }
    return;
  }
  // ---- GEMM role: gi in [0,1024); t fastest => A-panel shared by consecutive blocks ----
  int gi = (id / 3) * 2 + sel;
  int xblk = gi >> 5;                    // 0..31
  int t = gi & 31;
  int z, y;
  if (t < 16)      { z = 0; y = t; }
  else if (t < 24) { z = 1; y = t - 16; }
  else             { z = 2; y = t - 24; }
  const u16* A; const u16* Bt;
  if (z == 0)      { A = xb; Bt = WqT; }
  else if (z == 1) { A = eb; Bt = WkT; }
  else             { A = eb; Bt = WvT; }
  int m0 = xblk * 128, n0 = y * 64;

  f32x4 acc[2][4];
  gemm_bn64_core(A, Bt, 1024, As, Bs, m0, n0, acc);

  int tid = threadIdx.x;
  int w = tid >> 6, l = tid & 63;
  int g = l >> 4, lr = l & 15;
  int head = n0 >> 6;              // one head per block (BN=64)

  if (z == 2) {
    // V: rope + direct tiled+swizzled V^T store
#pragma unroll
    for (int m = 0; m < 2; ++m) {
      int rowb = m0 + w * 32 + m * 16 + g * 4;
#pragma unroll
      for (int r = 0; r < 4; ++r) {
        int row = rowb + r;
        int t2 = row & 1023, b = row >> 10;
        char* tbase = (char*)Vtiles + (size_t)((b * 8 + head) * 32 + (t2 >> 5)) * 4096;
        int kb = (t2 & 31) * 2;
#pragma unroll
        for (int n = 0; n < 4; ++n) {
          int dloc = n * 16 + lr;
          float v = acc[m][n][r];
          if (n < 2) {
            float cs = cstab[t2 * 32 + dloc];
            float sn = sntab[t2 * 32 + dloc];
            float partner = __shfl_xor(v, 1);
            float rot = (lr & 1) ? partner : -partner;
            v = v * cs + rot * sn;
          }
          int rr = dloc & 31;
          int scol = ((dloc >> 5) << 6) | kb;
          *(u16*)(tbase + rr * 128 + (scol ^ ((rr & 7) << 4))) = f2bf(v);
        }
      }
    }
    return;
  }

  const float* scale = (z == 0) ? qscale : kscale;
  float fs = (z == 0) ? 0.0015625f * LOG2E : 1.0f;
#pragma unroll
  for (int m = 0; m < 2; ++m) {
    int rowb = m0 + w * 32 + m * 16 + g * 4;
#pragma unroll
    for (int r = 0; r < 4; ++r) {
      int row = rowb + r;
      int t2 = row & 1023, b = row >> 10;
      float ss = 0.f;
#pragma unroll
      for (int n = 0; n < 4; ++n) { float v = acc[m][n][r]; ss += v * v; }
#pragma unroll
      for (int d = 1; d < 16; d <<= 1) ss += __shfl_xor(ss, d);
      float inv = 1.0f / fmaxf(sqrtf(ss), 1e-12f);
#pragma unroll
      for (int n = 0; n < 4; ++n) {
        int dloc = n * 16 + lr;
        float v = acc[m][n][r] * inv * scale[dloc];
        if (n < 2) {  // dloc < 32: rope (interleaved pairs = adjacent lr lanes)
          float cs = cstab[t2 * 32 + dloc];
          float sn = sntab[t2 * 32 + dloc];
          float partner = __shfl_xor(v, 1);
          float rot = (lr & 1) ? partner : -partner;
          v = v * cs + rot * sn;
        }
        v *= fs;
        if (z == 0) {
          Qb[((size_t)(b * 16 + head) * 1024 + t2) * 64 + dloc] = f2bf(v);
        } else {
          int tile = (b * 8 + head) * 32 + (t2 >> 5);
          int rin = t2 & 31;
          *(u16*)((char*)Ktiles + (size_t)tile * 4096 + rin * 128 + ((dloc * 2) ^ ((rin & 7) << 4))) = f2bf(v);
        }
      }
    }
  }
}

__global__ __launch_bounds__(256, 4) void gemm_out_kernel(const u16* Yb, const u16* WoT, float* out) {
  __shared__ __align__(16) u16 As[128 * 64];
  __shared__ __align__(16) u16 Bs[64 * 64];
  int id = blockIdx.x;
  int m0 = (id >> 4) * 128, n0 = (id & 15) * 64;   // n fastest: consecutive blocks share A panel
  f32x4 acc[2][4];
  gemm_bn64_core(Yb, WoT, 1024, As, Bs, m0, n0, acc);
  int tid = threadIdx.x;
  int w = tid >> 6, l = tid & 63;
  int g = l >> 4, lr = l & 15;
#pragma unroll
  for (int m = 0; m < 2; ++m)
#pragma unroll
    for (int n = 0; n < 4; ++n) {
      int row = m0 + w * 32 + m * 16 + g * 4;
      int col = n0 + n * 16 + lr;
#pragma unroll
      for (int r = 0; r < 4; ++r)
        out[(size_t)(row + r) * 1024 + col] = acc[m][n][r];
    }
}

// ---------------- flash attention: 4-wave split-K, m=0 softmax, counted-vmcnt staging ----------------
// Boundedness: q,k l2-normalized with all score scaling folded into Q => |q.k| <= 0.0023;
// |bias*LOG2E| <= ~0.17 for N(0,0.02). |p| <= 0.18 log2-units -> fixed m=0 exact.
__device__ __forceinline__ unsigned pack_bf2(float lo, float hi_) {
  union { __bf16 h[2]; unsigned u; } c;
  c.h[0] = (__bf16)lo; c.h[1] = (__bf16)hi_;
  return c.u;
}

__global__ __launch_bounds__(256, 4) void attn_kernel(const u16* __restrict__ Qb, const u16* __restrict__ Ktiles,
                                                      const u16* __restrict__ Vtiles, const u16* __restrict__ biasTT,
                                                      u16* __restrict__ Yb) {
  __shared__ __align__(16) char smem[33280];
  int tid = threadIdx.x;
  int w = tid >> 6;
  int lane = tid & 63;
  int ql = lane & 31;
  int hi = lane >> 5;
  int id = blockIdx.x;
  int xcd = id & 7;
  int j = id >> 3;
  int b = j & 3;
  int gslot = j >> 2;            // 0..63
  int g = gslot * 8 + xcd;       // 0..511
  int h = g & 15;
  int qt = 31 - (g >> 4);        // qt descending: long blocks first
  int kv = h & 7;
  int qg = qt * 32 + ql;
  int nt = qt + 1;

  char* stg = smem + w * 8192;

  const u16* Qrow = Qb + ((size_t)(b * 16 + h) * 1024 + qg) * 64;
  bf16x8 qf[4];
#pragma unroll
  for (int ks = 0; ks < 4; ++ks) qf[ks] = *(const bf16x8*)(Qrow + ks * 16 + hi * 8);

  const char* Ktb = (const char*)Ktiles + (size_t)((b * 8 + kv) * 32) * 4096;
  const char* Vtb = (const char*)Vtiles + (size_t)((b * 8 + kv) * 32) * 4096;
  const u16* btb = biasTT + (size_t)(h * 528 + qt * (qt + 1) / 2) * 1024;

  f32x16 o0, o1;
#pragma unroll
  for (int r = 0; r < 16; ++r) { o0[r] = 0.f; o1[r] = 0.f; }
  float lsum = 0.f;

  for (int it = w; it < nt; it += 4) {
    int t0 = it * 32;
    const char* Ksrc = Ktb + (size_t)it * 4096 + lane * 16;
    const char* Vsrc = Vtb + (size_t)it * 4096 + lane * 16;
#pragma unroll
    for (int i = 0; i < 4; ++i) load_lds16(Ksrc + i * 1024, stg + i * 1024);
#pragma unroll
    for (int i = 0; i < 4; ++i) load_lds16(Vsrc + i * 1024, stg + 4096 + i * 1024);
    __builtin_amdgcn_sched_barrier(0);
    asm volatile("s_waitcnt vmcnt(4)" ::: "memory"); // K complete; V still in flight
    __builtin_amdgcn_sched_barrier(0);
    const u16* bl = btb + (size_t)it * 1024 + lane * 16;
    bf16x8 ba = *(const bf16x8*)bl;
    bf16x8 bb2 = *(const bf16x8*)(bl + 8);
    f32x16 s;
#pragma unroll
    for (int r = 0; r < 16; ++r) s[r] = 0.f;
#pragma unroll
    for (int ks = 0; ks < 4; ++ks) {
      bf16x8 kc = *(const bf16x8*)(stg + ql * 128 + ((ks * 32 + hi * 16) ^ ((ql & 7) << 4)));
      s = __builtin_amdgcn_mfma_f32_32x32x16_bf16(kc, qf[ks], s, 0, 0, 0);
    }
    bool diag = (it == nt - 1);
    float p[16];
    float ssum = 0.f;
#pragma unroll
    for (int r = 0; r < 16; ++r) {
      float sv = s[r] + (float)(r < 8 ? ba[r & 7] : bb2[r & 7]);
      if (diag) {
        int key = t0 + (r & 3) + 8 * (r >> 2) + 4 * hi;
        if (key > qg) sv = -1e30f;
      }
      float pe = exp2f(sv);
      p[r] = pe;
      ssum += pe;
    }
    lsum += ssum;
    unsigned pk[8], tk[8];
#pragma unroll
    for (int j2 = 0; j2 < 8; ++j2) pk[j2] = pack_bf2(p[2 * j2], p[2 * j2 + 1]);
#pragma unroll
    for (int j2 = 0; j2 < 8; ++j2) tk[j2] = (unsigned)__shfl_xor((int)pk[j2], 32);
    union PU { unsigned u[4]; bf16x8 v; };
    PU pb0, pb1;
    pb0.u[0] = hi ? tk[2] : pk[0];
    pb0.u[1] = hi ? tk[3] : pk[1];
    pb0.u[2] = hi ? pk[2] : tk[0];
    pb0.u[3] = hi ? pk[3] : tk[1];
    pb1.u[0] = hi ? tk[6] : pk[4];
    pb1.u[1] = hi ? tk[7] : pk[5];
    pb1.u[2] = hi ? pk[6] : tk[4];
    pb1.u[3] = hi ? pk[7] : tk[5];
    asm volatile("s_waitcnt vmcnt(0)" ::: "memory");
    __builtin_amdgcn_sched_barrier(0);
    char* Vl = stg + 4096;
    bf16x8 v00 = *(const bf16x8*)(Vl + ql * 128 + (((0 << 6) | (0 * 32 + hi * 16)) ^ ((ql & 7) << 4)));
    bf16x8 v01 = *(const bf16x8*)(Vl + ql * 128 + (((0 << 6) | (1 * 32 + hi * 16)) ^ ((ql & 7) << 4)));
    bf16x8 v10 = *(const bf16x8*)(Vl + ql * 128 + (((1 << 6) | (0 * 32 + hi * 16)) ^ ((ql & 7) << 4)));
    bf16x8 v11 = *(const bf16x8*)(Vl + ql * 128 + (((1 << 6) | (1 * 32 + hi * 16)) ^ ((ql & 7) << 4)));
    o0 = __builtin_amdgcn_mfma_f32_32x32x16_bf16(v00, pb0.v, o0, 0, 0, 0);
    o0 = __builtin_amdgcn_mfma_f32_32x32x16_bf16(v01, pb1.v, o0, 0, 0, 0);
    o1 = __builtin_amdgcn_mfma_f32_32x32x16_bf16(v10, pb0.v, o1, 0, 0, 0);
    o1 = __builtin_amdgcn_mfma_f32_32x32x16_bf16(v11, pb1.v, o1, 0, 0, 0);
  }

  lsum += __shfl_xor(lsum, 32);
  u16* Osh = (u16*)stg;
  float* Lsh = (float*)(smem + 32768);
#pragma unroll
  for (int r = 0; r < 16; ++r) {
    int row = (r & 3) + 8 * (r >> 2) + 4 * hi;
    Osh[row * 32 + ql]        = f2bf(o0[r]);
    Osh[(row + 32) * 32 + ql] = f2bf(o1[r]);
  }
  if (hi == 0) Lsh[w * 32 + ql] = lsum;
  __syncthreads();

  {
    int q = tid & 31, dg = tid >> 5;
    float* Lsh2 = (float*)(smem + 32768);
    float ltot = Lsh2[q] + Lsh2[32 + q] + Lsh2[64 + q] + Lsh2[96 + q];
    float invl = 1.0f / ltot;
    u16 ov[8];
#pragma unroll
    for (int j2 = 0; j2 < 8; ++j2) {
      int d = dg * 8 + j2;
      float acc = bf2f(*(u16*)(smem + 0 * 8192 + (d * 32 + q) * 2)) +
                  bf2f(*(u16*)(smem + 1 * 8192 + (d * 32 + q) * 2)) +
                  bf2f(*(u16*)(smem + 2 * 8192 + (d * 32 + q) * 2)) +
                  bf2f(*(u16*)(smem + 3 * 8192 + (d * 32 + q) * 2));
      ov[j2] = f2bf(acc * invl);
    }
    ushort4 out0, out1;
    out0.x = ov[0]; out0.y = ov[1]; out0.z = ov[2]; out0.w = ov[3];
    out1.x = ov[4]; out1.y = ov[5]; out1.z = ov[6]; out1.w = ov[7];
    u16* Yp = Yb + ((size_t)b * 1024 + qt * 32 + q) * 1024 + h * 64 + dg * 8;
    *(ushort4*)Yp = out0;
    *(ushort4*)(Yp + 4) = out1;
  }
}

extern "C" void kernel_launch(void* const* d_in, const int* in_sizes, int n_in,
                              void* d_out, int out_size, void* d_ws, size_t ws_size,
                              hipStream_t stream) {
  const float* x     = (const float*)d_in[0];
  const float* enc   = (const float*)d_in[1];
  const float* freqs = (const float*)d_in[2];
  const float* bias  = (const float*)d_in[3];
  const float* Wq    = (const float*)d_in[4];
  const float* Wk    = (const float*)d_in[5];
  const float* Wv    = (const float*)d_in[6];
  const float* Wo    = (const float*)d_in[7];
  const float* qs    = (const float*)d_in[8];
  const float* ks    = (const float*)d_in[9];

  char* ws = (char*)d_ws;
  size_t off = 0;
  auto alloc = [&](size_t bytes) { char* p = ws + off; off += (bytes + 255) & ~(size_t)255; return p; };
  u16*   xb     = (u16*)alloc(8388608);     // x bf16 (4096 x 1024)
  u16*   eb     = (u16*)alloc(8388608);     // enc bf16
  u16*   WqT    = (u16*)alloc(2097152);
  u16*   WkT    = (u16*)alloc(1048576);
  u16*   WvT    = (u16*)alloc(1048576);
  u16*   WoT    = (u16*)alloc(2097152);
  u16*   Qb     = (u16*)alloc(8388608);     // (B,H,T,D) bf16
  u16*   Ktiles = (u16*)alloc(4194304);     // 1024 tiles x 4 KB (swizzled)
  u16*   Vtiles = (u16*)alloc(4194304);     // 1024 tiles x 4 KB (swizzled)
  u16*   biasTT = (u16*)alloc(17301504);    // 16 x 528 causal tiles x 2 KB
  float* cstab  = (float*)alloc(131072);
  float* sntab  = (float*)alloc(131072);
  u16*   Yb     = (u16*)xb;                 // alias: xb dead after QKV GEMM

  prologue_kernel<<<6272, 256, 0, stream>>>(x, enc, freqs, Wq, Wk, Wv, Wo,
                                            xb, eb, WqT, WkT, WvT, WoT, cstab, sntab);

  gemm_qkv_kernel<<<1536, 256, 0, stream>>>(xb, eb, WqT, WkT, WvT,
                                            qs, ks, cstab, sntab, bias,
                                            Qb, Ktiles, Vtiles, biasTT);

  attn_kernel<<<dim3(2048), 256, 0, stream>>>(Qb, Ktiles, Vtiles, biasTT, Yb);

  gemm_out_kernel<<<512, 256, 0, stream>>>(Yb, WoT, (float*)d_out);
}

// Round 15
// 93.789 us; speedup vs baseline: 1.1284x; 1.1284x over previous
//
#include <hip/hip_runtime.h>

typedef unsigned short u16;
typedef __attribute__((ext_vector_type(8))) __bf16 bf16x8;
typedef __attribute__((ext_vector_type(4))) float f32x4;
typedef __attribute__((ext_vector_type(16))) float f32x16;

#define LOG2E 1.44269504088896f

__device__ __forceinline__ u16 f2bf(float f) {
  union { float f; unsigned u; } c; c.f = f;
  unsigned u = c.u;
  return (u16)((u + 0x7fffu + ((u >> 16) & 1u)) >> 16);
}
__device__ __forceinline__ float bf2f(u16 h) {
  union { unsigned u; float f; } c; c.u = ((unsigned)h) << 16;
  return c.f;
}

__device__ __forceinline__ void load_lds16(const void* g, void* l) {
  __builtin_amdgcn_global_load_lds((const __attribute__((address_space(1))) unsigned int*)g,
                                   (__attribute__((address_space(3))) unsigned int*)l, 16, 0, 0);
}

// ---------------- merged prologue: cast x/enc -> bf16 | trig tables | weight transposes ----------------
__global__ void prologue_kernel(const float* __restrict__ x, const float* __restrict__ enc,
                                const float* __restrict__ freqs,
                                const float* __restrict__ Wq, const float* __restrict__ Wk,
                                const float* __restrict__ Wv, const float* __restrict__ Wo,
                                u16* __restrict__ xb, u16* __restrict__ eb,
                                u16* __restrict__ WqT, u16* __restrict__ WkT,
                                u16* __restrict__ WvT, u16* __restrict__ WoT,
                                float* __restrict__ cstab, float* __restrict__ sntab) {
  __shared__ float tile[32][33];
  int id = blockIdx.x;
  int tid = threadIdx.x;
  if (id < 2048) {
    const int n4each = 1048576;
    int stride = 2048 * 256;
    for (int i = id * 256 + tid; i < 2 * n4each; i += stride) {
      const float4* src; ushort4* dst; int j;
      if (i < n4each) { src = (const float4*)x; dst = (ushort4*)xb; j = i; }
      else            { src = (const float4*)enc; dst = (ushort4*)eb; j = i - n4each; }
      float4 v = src[j];
      ushort4 o;
      o.x = f2bf(v.x); o.y = f2bf(v.y); o.z = f2bf(v.z); o.w = f2bf(v.w);
      dst[j] = o;
    }
    return;
  }
  if (id < 2176) {
    int i = (id - 2048) * 256 + tid;
    float f = freqs[i];
    float sn, cs;
    sincosf(f, &sn, &cs);
    cstab[i] = cs; sntab[i] = sn;
    return;
  }
  int rem = id - 2176;
  int z = rem >> 10;
  int ry = (rem >> 5) & 31;
  int rx = rem & 31;
  const float* in; u16* out; int C;
  if (z == 0)      { in = Wq; out = WqT; C = 1024; }
  else if (z == 1) { in = Wk; out = WkT; C = 512; }
  else if (z == 2) { in = Wv; out = WvT; C = 512; }
  else             { in = Wo; out = WoT; C = 1024; }
  const int R = 1024;
  int c0 = rx * 32, r0 = ry * 32;
  if (c0 >= C) return;
  int tx = tid & 31, ty = tid >> 5;      // (32,8)
#pragma unroll
  for (int i = 0; i < 4; ++i)
    tile[ty + 8 * i][tx] = in[(size_t)(r0 + ty + 8 * i) * C + c0 + tx];
  __syncthreads();
#pragma unroll
  for (int i = 0; i < 4; ++i)
    out[(size_t)(c0 + ty + 8 * i) * R + r0 + tx] = f2bf(tile[tx][ty + 8 * i]);
}

// ---------------- 128x64 bf16 B^T GEMM core (single-buffer 24KB, BK=64, swizzled LDS) ----------------
__device__ __forceinline__ void gemm_bn64_core(const u16* A, const u16* Bt, int K,
                                               u16* As, u16* Bs, int m0, int n0,
                                               f32x4 (&acc)[2][4]) {
  int tid = threadIdx.x;
  int w = tid >> 6, l = tid & 63;
  int g = l >> 4, lr = l & 15;
#pragma unroll
  for (int m = 0; m < 2; ++m)
#pragma unroll
    for (int n = 0; n < 4; ++n) acc[m][n] = (f32x4){0.f, 0.f, 0.f, 0.f};

  for (int k0 = 0; k0 < K; k0 += 64) {
#pragma unroll
    for (int rnd = 0; rnd < 4; ++rnd) {
      int bidx = rnd * 4096 + w * 1024 + l * 16;
      int row = bidx >> 7, colb = bidx & 127;
      int scol = colb ^ ((row & 7) << 4);
      load_lds16((const char*)A + ((size_t)(m0 + row) * K + k0) * 2 + scol,
                 (char*)As + rnd * 4096 + w * 1024);
    }
#pragma unroll
    for (int rnd = 0; rnd < 2; ++rnd) {
      int bidx = rnd * 4096 + w * 1024 + l * 16;
      int row = bidx >> 7, colb = bidx & 127;
      int scol = colb ^ ((row & 7) << 4);
      load_lds16((const char*)Bt + ((size_t)(n0 + row) * K + k0) * 2 + scol,
                 (char*)Bs + rnd * 4096 + w * 1024);
    }
    __syncthreads();
    bf16x8 af[2][2], bfr[4][2];
#pragma unroll
    for (int m = 0; m < 2; ++m) {
      int ra = w * 32 + m * 16 + lr;
#pragma unroll
      for (int kf = 0; kf < 2; ++kf)
        af[m][kf] = *(const bf16x8*)((const char*)As + ra * 128 + ((kf * 64 + g * 16) ^ ((ra & 7) << 4)));
    }
#pragma unroll
    for (int n = 0; n < 4; ++n) {
      int rb = n * 16 + lr;
#pragma unroll
      for (int kf = 0; kf < 2; ++kf)
        bfr[n][kf] = *(const bf16x8*)((const char*)Bs + rb * 128 + ((kf * 64 + g * 16) ^ ((rb & 7) << 4)));
    }
#pragma unroll
    for (int m = 0; m < 2; ++m)
#pragma unroll
      for (int n = 0; n < 4; ++n) {
        acc[m][n] = __builtin_amdgcn_mfma_f32_16x16x32_bf16(af[m][0], bfr[n][0], acc[m][n], 0, 0, 0);
        acc[m][n] = __builtin_amdgcn_mfma_f32_16x16x32_bf16(af[m][1], bfr[n][1], acc[m][n], 0, 0, 0);
      }
    __syncthreads();
  }
}

// QKV GEMM (1-D grid, 1536 blocks): id%3==2 -> bias->tiles role interleaved in dispatch;
// GEMM decode keeps round-12's proven locality: xblk FASTEST (consecutive blocks share B panel).
__global__ __launch_bounds__(256, 4) void gemm_qkv_kernel(const u16* xb, const u16* eb,
                                                          const u16* WqT, const u16* WkT, const u16* WvT,
                                                          const float* __restrict__ qscale,
                                                          const float* __restrict__ kscale,
                                                          const float* __restrict__ cstab,
                                                          const float* __restrict__ sntab,
                                                          const float* __restrict__ bias,
                                                          u16* Qb, u16* Ktiles, u16* Vtiles,
                                                          u16* __restrict__ biasTT) {
  __shared__ __align__(16) char sh[24576];
  u16* As = (u16*)sh;              // 16 KB
  u16* Bs = (u16*)(sh + 16384);    // 8 KB
  int id = blockIdx.x;
  int sel = id % 3;
  if (sel == 2) {
    // ---- bias->causal-tiles role (512 blocks, woven through dispatch order) ----
    int flat = id / 3;                   // 0..511
    int w = threadIdx.x >> 6, lane = threadIdx.x & 63;
    float* lt = (float*)(sh + w * 4224); // 32x33 floats, wave-private
    int ql = lane & 31, hi = lane >> 5;
    for (int f = flat * 4 + w; f < 8448; f += 2048) {
      int h = f / 528, rem = f - h * 528;
      int qt = (int)((sqrtf(8.f * (float)rem + 1.f) - 1.f) * 0.5f);
      while ((qt + 1) * (qt + 2) / 2 <= rem) ++qt;
      while (qt * (qt + 1) / 2 > rem) --qt;
      int kt = rem - qt * (qt + 1) / 2;
      const float* tsrc = bias + ((size_t)h * 1024 + qt * 32) * 1024 + kt * 32;
#pragma unroll
      for (int i = 0; i < 4; ++i) {
        int row = i * 8 + (lane >> 3);
        int c4 = (lane & 7) * 4;
        float4 v4 = *(const float4*)(tsrc + (size_t)row * 1024 + c4);
        lt[row * 33 + c4 + 0] = v4.x; lt[row * 33 + c4 + 1] = v4.y;
        lt[row * 33 + c4 + 2] = v4.z; lt[row * 33 + c4 + 3] = v4.w;
      }
      u16 v[16];
#pragma unroll
      for (int r = 0; r < 16; ++r) {
        int c = (r & 3) + 8 * (r >> 2) + 4 * hi;
        v[r] = f2bf(lt[ql * 33 + c] * LOG2E);
      }
      u16* dst = biasTT + (size_t)f * 1024 + lane * 16;
#pragma unroll
      for (int i = 0; i < 4; ++i) {
        ushort4 o; o.x = v[i * 4]; o.y = v[i * 4 + 1]; o.z = v[i * 4 + 2]; o.w = v[i * 4 + 3];
        *(ushort4*)(dst + i * 4) = o;
      }
    }
    return;
  }
  // ---- GEMM role: gi in [0,1024); xblk fastest (round-12 locality) ----
  int gi = (id / 3) * 2 + sel;
  int xblk = gi & 31;                    // fastest
  int t = gi >> 5;                       // 0..31
  int z, y;
  if (t < 16)      { z = 0; y = t; }
  else if (t < 24) { z = 1; y = t - 16; }
  else             { z = 2; y = t - 24; }
  const u16* A; const u16* Bt;
  if (z == 0)      { A = xb; Bt = WqT; }
  else if (z == 1) { A = eb; Bt = WkT; }
  else             { A = eb; Bt = WvT; }
  int m0 = xblk * 128, n0 = y * 64;

  f32x4 acc[2][4];
  gemm_bn64_core(A, Bt, 1024, As, Bs, m0, n0, acc);

  int tid = threadIdx.x;
  int w = tid >> 6, l = tid & 63;
  int g = l >> 4, lr = l & 15;
  int head = n0 >> 6;              // one head per block (BN=64)

  if (z == 2) {
    // V: rope + direct tiled+swizzled V^T store
#pragma unroll
    for (int m = 0; m < 2; ++m) {
      int rowb = m0 + w * 32 + m * 16 + g * 4;
#pragma unroll
      for (int r = 0; r < 4; ++r) {
        int row = rowb + r;
        int t2 = row & 1023, b = row >> 10;
        char* tbase = (char*)Vtiles + (size_t)((b * 8 + head) * 32 + (t2 >> 5)) * 4096;
        int kb = (t2 & 31) * 2;
#pragma unroll
        for (int n = 0; n < 4; ++n) {
          int dloc = n * 16 + lr;
          float v = acc[m][n][r];
          if (n < 2) {
            float cs = cstab[t2 * 32 + dloc];
            float sn = sntab[t2 * 32 + dloc];
            float partner = __shfl_xor(v, 1);
            float rot = (lr & 1) ? partner : -partner;
            v = v * cs + rot * sn;
          }
          int rr = dloc & 31;
          int scol = ((dloc >> 5) << 6) | kb;
          *(u16*)(tbase + rr * 128 + (scol ^ ((rr & 7) << 4))) = f2bf(v);
        }
      }
    }
    return;
  }

  const float* scale = (z == 0) ? qscale : kscale;
  float fs = (z == 0) ? 0.0015625f * LOG2E : 1.0f;
#pragma unroll
  for (int m = 0; m < 2; ++m) {
    int rowb = m0 + w * 32 + m * 16 + g * 4;
#pragma unroll
    for (int r = 0; r < 4; ++r) {
      int row = rowb + r;
      int t2 = row & 1023, b = row >> 10;
      float ss = 0.f;
#pragma unroll
      for (int n = 0; n < 4; ++n) { float v = acc[m][n][r]; ss += v * v; }
#pragma unroll
      for (int d = 1; d < 16; d <<= 1) ss += __shfl_xor(ss, d);
      float inv = 1.0f / fmaxf(sqrtf(ss), 1e-12f);
#pragma unroll
      for (int n = 0; n < 4; ++n) {
        int dloc = n * 16 + lr;
        float v = acc[m][n][r] * inv * scale[dloc];
        if (n < 2) {  // dloc < 32: rope (interleaved pairs = adjacent lr lanes)
          float cs = cstab[t2 * 32 + dloc];
          float sn = sntab[t2 * 32 + dloc];
          float partner = __shfl_xor(v, 1);
          float rot = (lr & 1) ? partner : -partner;
          v = v * cs + rot * sn;
        }
        v *= fs;
        if (z == 0) {
          Qb[((size_t)(b * 16 + head) * 1024 + t2) * 64 + dloc] = f2bf(v);
        } else {
          int tile = (b * 8 + head) * 32 + (t2 >> 5);
          int rin = t2 & 31;
          *(u16*)((char*)Ktiles + (size_t)tile * 4096 + rin * 128 + ((dloc * 2) ^ ((rin & 7) << 4))) = f2bf(v);
        }
      }
    }
  }
}

__global__ __launch_bounds__(256, 4) void gemm_out_kernel(const u16* Yb, const u16* WoT, float* out) {
  __shared__ __align__(16) u16 As[128 * 64];
  __shared__ __align__(16) u16 Bs[64 * 64];
  int id = blockIdx.x;
  int m0 = (id & 31) * 128, n0 = (id >> 5) * 64;   // xblk fastest (round-12 locality)
  f32x4 acc[2][4];
  gemm_bn64_core(Yb, WoT, 1024, As, Bs, m0, n0, acc);
  int tid = threadIdx.x;
  int w = tid >> 6, l = tid & 63;
  int g = l >> 4, lr = l & 15;
#pragma unroll
  for (int m = 0; m < 2; ++m)
#pragma unroll
    for (int n = 0; n < 4; ++n) {
      int row = m0 + w * 32 + m * 16 + g * 4;
      int col = n0 + n * 16 + lr;
#pragma unroll
      for (int r = 0; r < 4; ++r)
        out[(size_t)(row + r) * 1024 + col] = acc[m][n][r];
    }
}

// ---------------- flash attention: 4-wave split-K, m=0 softmax, counted-vmcnt staging ----------------
// Boundedness: q,k l2-normalized with all score scaling folded into Q => |q.k| <= 0.0023;
// |bias*LOG2E| <= ~0.17 for N(0,0.02). |p| <= 0.18 log2-units -> fixed m=0 exact.
__device__ __forceinline__ unsigned pack_bf2(float lo, float hi_) {
  union { __bf16 h[2]; unsigned u; } c;
  c.h[0] = (__bf16)lo; c.h[1] = (__bf16)hi_;
  return c.u;
}

__global__ __launch_bounds__(256, 4) void attn_kernel(const u16* __restrict__ Qb, const u16* __restrict__ Ktiles,
                                                      const u16* __restrict__ Vtiles, const u16* __restrict__ biasTT,
                                                      u16* __restrict__ Yb) {
  __shared__ __align__(16) char smem[33280];
  int tid = threadIdx.x;
  int w = tid >> 6;
  int lane = tid & 63;
  int ql = lane & 31;
  int hi = lane >> 5;
  int id = blockIdx.x;
  int xcd = id & 7;
  int j = id >> 3;
  int b = j & 3;
  int gslot = j >> 2;            // 0..63
  int g = gslot * 8 + xcd;       // 0..511
  int h = g & 15;
  int qt = 31 - (g >> 4);        // qt descending: long blocks first
  int kv = h & 7;
  int qg = qt * 32 + ql;
  int nt = qt + 1;

  char* stg = smem + w * 8192;

  const u16* Qrow = Qb + ((size_t)(b * 16 + h) * 1024 + qg) * 64;
  bf16x8 qf[4];
#pragma unroll
  for (int ks = 0; ks < 4; ++ks) qf[ks] = *(const bf16x8*)(Qrow + ks * 16 + hi * 8);

  const char* Ktb = (const char*)Ktiles + (size_t)((b * 8 + kv) * 32) * 4096;
  const char* Vtb = (const char*)Vtiles + (size_t)((b * 8 + kv) * 32) * 4096;
  const u16* btb = biasTT + (size_t)(h * 528 + qt * (qt + 1) / 2) * 1024;

  f32x16 o0, o1;
#pragma unroll
  for (int r = 0; r < 16; ++r) { o0[r] = 0.f; o1[r] = 0.f; }
  float lsum = 0.f;

  for (int it = w; it < nt; it += 4) {
    int t0 = it * 32;
    const char* Ksrc = Ktb + (size_t)it * 4096 + lane * 16;
    const char* Vsrc = Vtb + (size_t)it * 4096 + lane * 16;
#pragma unroll
    for (int i = 0; i < 4; ++i) load_lds16(Ksrc + i * 1024, stg + i * 1024);
#pragma unroll
    for (int i = 0; i < 4; ++i) load_lds16(Vsrc + i * 1024, stg + 4096 + i * 1024);
    __builtin_amdgcn_sched_barrier(0);
    asm volatile("s_waitcnt vmcnt(4)" ::: "memory"); // K complete; V still in flight
    __builtin_amdgcn_sched_barrier(0);
    const u16* bl = btb + (size_t)it * 1024 + lane * 16;
    bf16x8 ba = *(const bf16x8*)bl;
    bf16x8 bb2 = *(const bf16x8*)(bl + 8);
    f32x16 s;
#pragma unroll
    for (int r = 0; r < 16; ++r) s[r] = 0.f;
#pragma unroll
    for (int ks = 0; ks < 4; ++ks) {
      bf16x8 kc = *(const bf16x8*)(stg + ql * 128 + ((ks * 32 + hi * 16) ^ ((ql & 7) << 4)));
      s = __builtin_amdgcn_mfma_f32_32x32x16_bf16(kc, qf[ks], s, 0, 0, 0);
    }
    bool diag = (it == nt - 1);
    float p[16];
    float ssum = 0.f;
#pragma unroll
    for (int r = 0; r < 16; ++r) {
      float sv = s[r] + (float)(r < 8 ? ba[r & 7] : bb2[r & 7]);
      if (diag) {
        int key = t0 + (r & 3) + 8 * (r >> 2) + 4 * hi;
        if (key > qg) sv = -1e30f;
      }
      float pe = exp2f(sv);
      p[r] = pe;
      ssum += pe;
    }
    lsum += ssum;
    unsigned pk[8], tk[8];
#pragma unroll
    for (int j2 = 0; j2 < 8; ++j2) pk[j2] = pack_bf2(p[2 * j2], p[2 * j2 + 1]);
#pragma unroll
    for (int j2 = 0; j2 < 8; ++j2) tk[j2] = (unsigned)__shfl_xor((int)pk[j2], 32);
    union PU { unsigned u[4]; bf16x8 v; };
    PU pb0, pb1;
    pb0.u[0] = hi ? tk[2] : pk[0];
    pb0.u[1] = hi ? tk[3] : pk[1];
    pb0.u[2] = hi ? pk[2] : tk[0];
    pb0.u[3] = hi ? pk[3] : tk[1];
    pb1.u[0] = hi ? tk[6] : pk[4];
    pb1.u[1] = hi ? tk[7] : pk[5];
    pb1.u[2] = hi ? pk[6] : tk[4];
    pb1.u[3] = hi ? pk[7] : tk[5];
    asm volatile("s_waitcnt vmcnt(0)" ::: "memory");
    __builtin_amdgcn_sched_barrier(0);
    char* Vl = stg + 4096;
    bf16x8 v00 = *(const bf16x8*)(Vl + ql * 128 + (((0 << 6) | (0 * 32 + hi * 16)) ^ ((ql & 7) << 4)));
    bf16x8 v01 = *(const bf16x8*)(Vl + ql * 128 + (((0 << 6) | (1 * 32 + hi * 16)) ^ ((ql & 7) << 4)));
    bf16x8 v10 = *(const bf16x8*)(Vl + ql * 128 + (((1 << 6) | (0 * 32 + hi * 16)) ^ ((ql & 7) << 4)));
    bf16x8 v11 = *(const bf16x8*)(Vl + ql * 128 + (((1 << 6) | (1 * 32 + hi * 16)) ^ ((ql & 7) << 4)));
    o0 = __builtin_amdgcn_mfma_f32_32x32x16_bf16(v00, pb0.v, o0, 0, 0, 0);
    o0 = __builtin_amdgcn_mfma_f32_32x32x16_bf16(v01, pb1.v, o0, 0, 0, 0);
    o1 = __builtin_amdgcn_mfma_f32_32x32x16_bf16(v10, pb0.v, o1, 0, 0, 0);
    o1 = __builtin_amdgcn_mfma_f32_32x32x16_bf16(v11, pb1.v, o1, 0, 0, 0);
  }

  lsum += __shfl_xor(lsum, 32);
  u16* Osh = (u16*)stg;
  float* Lsh = (float*)(smem + 32768);
#pragma unroll
  for (int r = 0; r < 16; ++r) {
    int row = (r & 3) + 8 * (r >> 2) + 4 * hi;
    Osh[row * 32 + ql]        = f2bf(o0[r]);
    Osh[(row + 32) * 32 + ql] = f2bf(o1[r]);
  }
  if (hi == 0) Lsh[w * 32 + ql] = lsum;
  __syncthreads();

  {
    int q = tid & 31, dg = tid >> 5;
    float* Lsh2 = (float*)(smem + 32768);
    float ltot = Lsh2[q] + Lsh2[32 + q] + Lsh2[64 + q] + Lsh2[96 + q];
    float invl = 1.0f / ltot;
    u16 ov[8];
#pragma unroll
    for (int j2 = 0; j2 < 8; ++j2) {
      int d = dg * 8 + j2;
      float acc = bf2f(*(u16*)(smem + 0 * 8192 + (d * 32 + q) * 2)) +
                  bf2f(*(u16*)(smem + 1 * 8192 + (d * 32 + q) * 2)) +
                  bf2f(*(u16*)(smem + 2 * 8192 + (d * 32 + q) * 2)) +
                  bf2f(*(u16*)(smem + 3 * 8192 + (d * 32 + q) * 2));
      ov[j2] = f2bf(acc * invl);
    }
    ushort4 out0, out1;
    out0.x = ov[0]; out0.y = ov[1]; out0.z = ov[2]; out0.w = ov[3];
    out1.x = ov[4]; out1.y = ov[5]; out1.z = ov[6]; out1.w = ov[7];
    u16* Yp = Yb + ((size_t)b * 1024 + qt * 32 + q) * 1024 + h * 64 + dg * 8;
    *(ushort4*)Yp = out0;
    *(ushort4*)(Yp + 4) = out1;
  }
}

extern "C" void kernel_launch(void* const* d_in, const int* in_sizes, int n_in,
                              void* d_out, int out_size, void* d_ws, size_t ws_size,
                              hipStream_t stream) {
  const float* x     = (const float*)d_in[0];
  const float* enc   = (const float*)d_in[1];
  const float* freqs = (const float*)d_in[2];
  const float* bias  = (const float*)d_in[3];
  const float* Wq    = (const float*)d_in[4];
  const float* Wk    = (const float*)d_in[5];
  const float* Wv    = (const float*)d_in[6];
  const float* Wo    = (const float*)d_in[7];
  const float* qs    = (const float*)d_in[8];
  const float* ks    = (const float*)d_in[9];

  char* ws = (char*)d_ws;
  size_t off = 0;
  auto alloc = [&](size_t bytes) { char* p = ws + off; off += (bytes + 255) & ~(size_t)255; return p; };
  u16*   xb     = (u16*)alloc(8388608);     // x bf16 (4096 x 1024)
  u16*   eb     = (u16*)alloc(8388608);     // enc bf16
  u16*   WqT    = (u16*)alloc(2097152);
  u16*   WkT    = (u16*)alloc(1048576);
  u16*   WvT    = (u16*)alloc(1048576);
  u16*   WoT    = (u16*)alloc(2097152);
  u16*   Qb     = (u16*)alloc(8388608);     // (B,H,T,D) bf16
  u16*   Ktiles = (u16*)alloc(4194304);     // 1024 tiles x 4 KB (swizzled)
  u16*   Vtiles = (u16*)alloc(4194304);     // 1024 tiles x 4 KB (swizzled)
  u16*   biasTT = (u16*)alloc(17301504);    // 16 x 528 causal tiles x 2 KB
  float* cstab  = (float*)alloc(131072);
  float* sntab  = (float*)alloc(131072);
  u16*   Yb     = (u16*)xb;                 // alias: xb dead after QKV GEMM

  prologue_kernel<<<6272, 256, 0, stream>>>(x, enc, freqs, Wq, Wk, Wv, Wo,
                                            xb, eb, WqT, WkT, WvT, WoT, cstab, sntab);

  gemm_qkv_kernel<<<1536, 256, 0, stream>>>(xb, eb, WqT, WkT, WvT,
                                            qs, ks, cstab, sntab, bias,
                                            Qb, Ktiles, Vtiles, biasTT);

  attn_kernel<<<dim3(2048), 256, 0, stream>>>(Qb, Ktiles, Vtiles, biasTT, Yb);

  gemm_out_kernel<<<512, 256, 0, stream>>>(Yb, WoT, (float*)d_out);
}

// Round 16
// 89.651 us; speedup vs baseline: 1.1805x; 1.0462x over previous
//
#include <hip/hip_runtime.h>

typedef unsigned short u16;
typedef __attribute__((ext_vector_type(8))) __bf16 bf16x8;
typedef __attribute__((ext_vector_type(4))) float f32x4;
typedef __attribute__((ext_vector_type(16))) float f32x16;

#define LOG2E 1.44269504088896f

__device__ __forceinline__ u16 f2bf(float f) {
  union { float f; unsigned u; } c; c.f = f;
  unsigned u = c.u;
  return (u16)((u + 0x7fffu + ((u >> 16) & 1u)) >> 16);
}
__device__ __forceinline__ float bf2f(u16 h) {
  union { unsigned u; float f; } c; c.u = ((unsigned)h) << 16;
  return c.f;
}

__device__ __forceinline__ void load_lds16(const void* g, void* l) {
  __builtin_amdgcn_global_load_lds((const __attribute__((address_space(1))) unsigned int*)g,
                                   (__attribute__((address_space(3))) unsigned int*)l, 16, 0, 0);
}

// ---------------- merged prologue: cast x/enc -> bf16 | trig tables | weight transposes ----------------
__global__ void prologue_kernel(const float* __restrict__ x, const float* __restrict__ enc,
                                const float* __restrict__ freqs,
                                const float* __restrict__ Wq, const float* __restrict__ Wk,
                                const float* __restrict__ Wv, const float* __restrict__ Wo,
                                u16* __restrict__ xb, u16* __restrict__ eb,
                                u16* __restrict__ WqT, u16* __restrict__ WkT,
                                u16* __restrict__ WvT, u16* __restrict__ WoT,
                                float* __restrict__ cstab, float* __restrict__ sntab) {
  __shared__ float tile[32][33];
  int id = blockIdx.x;
  int tid = threadIdx.x;
  if (id < 2048) {
    // cast role: 2 x 1048576 float4, stride 2048*256
    const int n4each = 1048576;
    int stride = 2048 * 256;
    for (int i = id * 256 + tid; i < 2 * n4each; i += stride) {
      const float4* src; ushort4* dst; int j;
      if (i < n4each) { src = (const float4*)x; dst = (ushort4*)xb; j = i; }
      else            { src = (const float4*)enc; dst = (ushort4*)eb; j = i - n4each; }
      float4 v = src[j];
      ushort4 o;
      o.x = f2bf(v.x); o.y = f2bf(v.y); o.z = f2bf(v.z); o.w = f2bf(v.w);
      dst[j] = o;
    }
    return;
  }
  if (id < 2176) {
    int i = (id - 2048) * 256 + tid;     // 32768 entries
    float f = freqs[i];
    float sn, cs;
    sincosf(f, &sn, &cs);
    cstab[i] = cs; sntab[i] = sn;
    return;
  }
  // transpose role: 4096 blocks -> z in [0,4), y in [0,32), x in [0,32)
  int rem = id - 2176;
  int z = rem >> 10;
  int ry = (rem >> 5) & 31;
  int rx = rem & 31;
  const float* in; u16* out; int C;
  if (z == 0)      { in = Wq; out = WqT; C = 1024; }
  else if (z == 1) { in = Wk; out = WkT; C = 512; }
  else if (z == 2) { in = Wv; out = WvT; C = 512; }
  else             { in = Wo; out = WoT; C = 1024; }
  const int R = 1024;
  int c0 = rx * 32, r0 = ry * 32;
  if (c0 >= C) return;
  int tx = tid & 31, ty = tid >> 5;      // (32,8)
#pragma unroll
  for (int i = 0; i < 4; ++i)
    tile[ty + 8 * i][tx] = in[(size_t)(r0 + ty + 8 * i) * C + c0 + tx];
  __syncthreads();
#pragma unroll
  for (int i = 0; i < 4; ++i)
    out[(size_t)(c0 + ty + 8 * i) * R + r0 + tx] = f2bf(tile[tx][ty + 8 * i]);
}

// ---------------- 128x64 bf16 B^T GEMM core (BK=64, swizzled LDS, 4 waves stacked) ----------------
// Wave w owns output rows [w*32, w*32+32) x all 64 cols -> epilogue reductions stay in-wave.
__device__ __forceinline__ void gemm_bn64_core(const u16* A, const u16* Bt, int K,
                                               u16* As, u16* Bs, f32x4 (&acc)[2][4]) {
  int tid = threadIdx.x;
  int w = tid >> 6, l = tid & 63;
  int g = l >> 4, lr = l & 15;
  int m0 = blockIdx.x * 128, n0 = blockIdx.y * 64;
#pragma unroll
  for (int m = 0; m < 2; ++m)
#pragma unroll
    for (int n = 0; n < 4; ++n) acc[m][n] = (f32x4){0.f, 0.f, 0.f, 0.f};

  for (int k0 = 0; k0 < K; k0 += 64) {
#pragma unroll
    for (int rnd = 0; rnd < 4; ++rnd) {
      int bidx = rnd * 4096 + w * 1024 + l * 16;
      int row = bidx >> 7, colb = bidx & 127;
      int scol = colb ^ ((row & 7) << 4);
      load_lds16((const char*)A + ((size_t)(m0 + row) * K + k0) * 2 + scol,
                 (char*)As + rnd * 4096 + w * 1024);
    }
#pragma unroll
    for (int rnd = 0; rnd < 2; ++rnd) {
      int bidx = rnd * 4096 + w * 1024 + l * 16;
      int row = bidx >> 7, colb = bidx & 127;
      int scol = colb ^ ((row & 7) << 4);
      load_lds16((const char*)Bt + ((size_t)(n0 + row) * K + k0) * 2 + scol,
                 (char*)Bs + rnd * 4096 + w * 1024);
    }
    __syncthreads();
    bf16x8 af[2][2], bfr[4][2];
#pragma unroll
    for (int m = 0; m < 2; ++m) {
      int ra = w * 32 + m * 16 + lr;
#pragma unroll
      for (int kf = 0; kf < 2; ++kf)
        af[m][kf] = *(const bf16x8*)((const char*)As + ra * 128 + ((kf * 64 + g * 16) ^ ((ra & 7) << 4)));
    }
#pragma unroll
    for (int n = 0; n < 4; ++n) {
      int rb = n * 16 + lr;
#pragma unroll
      for (int kf = 0; kf < 2; ++kf)
        bfr[n][kf] = *(const bf16x8*)((const char*)Bs + rb * 128 + ((kf * 64 + g * 16) ^ ((rb & 7) << 4)));
    }
#pragma unroll
    for (int m = 0; m < 2; ++m)
#pragma unroll
      for (int n = 0; n < 4; ++n) {
        acc[m][n] = __builtin_amdgcn_mfma_f32_16x16x32_bf16(af[m][0], bfr[n][0], acc[m][n], 0, 0, 0);
        acc[m][n] = __builtin_amdgcn_mfma_f32_16x16x32_bf16(af[m][1], bfr[n][1], acc[m][n], 0, 0, 0);
      }
    __syncthreads();
  }
}

// QKV GEMM with fused epilogues (Q/K: l2norm+scale+rope; V: rope+tiled store).
// The 512 culled blocks (z=1,2 with y>=8) run the bias->tiles conversion instead.
__global__ __launch_bounds__(256, 4) void gemm_qkv_kernel(const u16* xb, const u16* eb,
                                                          const u16* WqT, const u16* WkT, const u16* WvT,
                                                          const float* __restrict__ qscale,
                                                          const float* __restrict__ kscale,
                                                          const float* __restrict__ cstab,
                                                          const float* __restrict__ sntab,
                                                          const float* __restrict__ bias,
                                                          u16* Qb, u16* Ktiles, u16* Vtiles,
                                                          u16* __restrict__ biasTT) {
  __shared__ __align__(16) char sh[24576];
  u16* As = (u16*)sh;              // 16 KB
  u16* Bs = (u16*)(sh + 16384);    // 8 KB
  int z = blockIdx.z;
  const u16* A; const u16* Bt; int N;
  if (z == 0)      { A = xb; Bt = WqT; N = 1024; }
  else if (z == 1) { A = eb; Bt = WkT; N = 512; }
  else             { A = eb; Bt = WvT; N = 512; }

  if ((int)blockIdx.y * 64 >= N) {
    // ---- bias->causal-tiles path on otherwise-idle blocks ----
    int flat = (z - 1) * 256 + ((int)blockIdx.y - 8) * 32 + (int)blockIdx.x;
    int w = threadIdx.x >> 6, lane = threadIdx.x & 63;
    float* lt = (float*)(sh + w * 4224);   // 32x33 floats, wave-private
    int ql = lane & 31, hi = lane >> 5;
    for (int f = flat * 4 + w; f < 8448; f += 2048) {
      int h = f / 528, rem = f - h * 528;
      int qt = (int)((sqrtf(8.f * (float)rem + 1.f) - 1.f) * 0.5f);
      while ((qt + 1) * (qt + 2) / 2 <= rem) ++qt;
      while (qt * (qt + 1) / 2 > rem) --qt;
      int kt = rem - qt * (qt + 1) / 2;
      const float* tsrc = bias + ((size_t)h * 1024 + qt * 32) * 1024 + kt * 32;
#pragma unroll
      for (int i = 0; i < 4; ++i) {
        int row = i * 8 + (lane >> 3);
        int c4 = (lane & 7) * 4;
        float4 v4 = *(const float4*)(tsrc + (size_t)row * 1024 + c4);
        lt[row * 33 + c4 + 0] = v4.x; lt[row * 33 + c4 + 1] = v4.y;
        lt[row * 33 + c4 + 2] = v4.z; lt[row * 33 + c4 + 3] = v4.w;
      }
      u16 v[16];
#pragma unroll
      for (int r = 0; r < 16; ++r) {
        int c = (r & 3) + 8 * (r >> 2) + 4 * hi;
        v[r] = f2bf(lt[ql * 33 + c] * LOG2E);
      }
      u16* dst = biasTT + (size_t)f * 1024 + lane * 16;
#pragma unroll
      for (int i = 0; i < 4; ++i) {
        ushort4 o; o.x = v[i * 4]; o.y = v[i * 4 + 1]; o.z = v[i * 4 + 2]; o.w = v[i * 4 + 3];
        *(ushort4*)(dst + i * 4) = o;
      }
    }
    return;
  }

  f32x4 acc[2][4];
  gemm_bn64_core(A, Bt, 1024, As, Bs, acc);

  int tid = threadIdx.x;
  int w = tid >> 6, l = tid & 63;
  int g = l >> 4, lr = l & 15;
  int m0 = blockIdx.x * 128, n0 = blockIdx.y * 64;
  int head = n0 >> 6;              // one head per block (BN=64)

  if (z == 2) {
    // V: rope + direct tiled+swizzled V^T store
#pragma unroll
    for (int m = 0; m < 2; ++m) {
      int rowb = m0 + w * 32 + m * 16 + g * 4;
#pragma unroll
      for (int r = 0; r < 4; ++r) {
        int row = rowb + r;
        int t2 = row & 1023, b = row >> 10;
        char* tbase = (char*)Vtiles + (size_t)((b * 8 + head) * 32 + (t2 >> 5)) * 4096;
        int kb = (t2 & 31) * 2;
#pragma unroll
        for (int n = 0; n < 4; ++n) {
          int dloc = n * 16 + lr;
          float v = acc[m][n][r];
          if (n < 2) {
            float cs = cstab[t2 * 32 + dloc];
            float sn = sntab[t2 * 32 + dloc];
            float partner = __shfl_xor(v, 1);
            float rot = (lr & 1) ? partner : -partner;
            v = v * cs + rot * sn;
          }
          int rr = dloc & 31;
          int scol = ((dloc >> 5) << 6) | kb;
          *(u16*)(tbase + rr * 128 + (scol ^ ((rr & 7) << 4))) = f2bf(v);
        }
      }
    }
    return;
  }

  const float* scale = (z == 0) ? qscale : kscale;
  float fs = (z == 0) ? 0.0015625f * LOG2E : 1.0f;
#pragma unroll
  for (int m = 0; m < 2; ++m) {
    int rowb = m0 + w * 32 + m * 16 + g * 4;
#pragma unroll
    for (int r = 0; r < 4; ++r) {
      int row = rowb + r;
      int t2 = row & 1023, b = row >> 10;
      float ss = 0.f;
#pragma unroll
      for (int n = 0; n < 4; ++n) { float v = acc[m][n][r]; ss += v * v; }
#pragma unroll
      for (int d = 1; d < 16; d <<= 1) ss += __shfl_xor(ss, d);
      float inv = 1.0f / fmaxf(sqrtf(ss), 1e-12f);
#pragma unroll
      for (int n = 0; n < 4; ++n) {
        int dloc = n * 16 + lr;
        float v = acc[m][n][r] * inv * scale[dloc];
        if (n < 2) {  // dloc < 32: rope (interleaved pairs = adjacent lr lanes)
          float cs = cstab[t2 * 32 + dloc];
          float sn = sntab[t2 * 32 + dloc];
          float partner = __shfl_xor(v, 1);
          float rot = (lr & 1) ? partner : -partner;
          v = v * cs + rot * sn;
        }
        v *= fs;
        if (z == 0) {
          Qb[((size_t)(b * 16 + head) * 1024 + t2) * 64 + dloc] = f2bf(v);
        } else {
          int tile = (b * 8 + head) * 32 + (t2 >> 5);
          int rin = t2 & 31;
          *(u16*)((char*)Ktiles + (size_t)tile * 4096 + rin * 128 + ((dloc * 2) ^ ((rin & 7) << 4))) = f2bf(v);
        }
      }
    }
  }
}

__global__ __launch_bounds__(256, 4) void gemm_out_kernel(const u16* Yb, const u16* WoT, float* out) {
  __shared__ __align__(16) u16 As[128 * 64];
  __shared__ __align__(16) u16 Bs[64 * 64];
  f32x4 acc[2][4];
  gemm_bn64_core(Yb, WoT, 1024, As, Bs, acc);
  int tid = threadIdx.x;
  int w = tid >> 6, l = tid & 63;
  int g = l >> 4, lr = l & 15;
  int m0 = blockIdx.x * 128, n0 = blockIdx.y * 64;
#pragma unroll
  for (int m = 0; m < 2; ++m)
#pragma unroll
    for (int n = 0; n < 4; ++n) {
      int row = m0 + w * 32 + m * 16 + g * 4;
      int col = n0 + n * 16 + lr;
#pragma unroll
      for (int r = 0; r < 4; ++r)
        out[(size_t)(row + r) * 1024 + col] = acc[m][n][r];
    }
}

// ---------------- flash attention: 4-wave split-K, m=0 softmax, counted-vmcnt staging ----------------
// Boundedness: q,k l2-normalized with all score scaling folded into Q => |q.k| <= 0.0023;
// |bias*LOG2E| <= ~0.17 for N(0,0.02). |p| <= 0.18 log2-units -> fixed m=0 exact.
__device__ __forceinline__ unsigned pack_bf2(float lo, float hi_) {
  union { __bf16 h[2]; unsigned u; } c;
  c.h[0] = (__bf16)lo; c.h[1] = (__bf16)hi_;
  return c.u;
}

__global__ __launch_bounds__(256, 4) void attn_kernel(const u16* __restrict__ Qb, const u16* __restrict__ Ktiles,
                                                      const u16* __restrict__ Vtiles, const u16* __restrict__ biasTT,
                                                      u16* __restrict__ Yb) {
  __shared__ __align__(16) char smem[33280];
  int tid = threadIdx.x;
  int w = tid >> 6;
  int lane = tid & 63;
  int ql = lane & 31;
  int hi = lane >> 5;
  int id = blockIdx.x;
  int xcd = id & 7;
  int j = id >> 3;
  int b = j & 3;
  int gslot = j >> 2;            // 0..63
  int g = gslot * 8 + xcd;       // 0..511
  int h = g & 15;
  int qt = 31 - (g >> 4);        // qt descending: long blocks first
  int kv = h & 7;
  int qg = qt * 32 + ql;
  int nt = qt + 1;

  char* stg = smem + w * 8192;

  const u16* Qrow = Qb + ((size_t)(b * 16 + h) * 1024 + qg) * 64;
  bf16x8 qf[4];
#pragma unroll
  for (int ks = 0; ks < 4; ++ks) qf[ks] = *(const bf16x8*)(Qrow + ks * 16 + hi * 8);

  const char* Ktb = (const char*)Ktiles + (size_t)((b * 8 + kv) * 32) * 4096;
  const char* Vtb = (const char*)Vtiles + (size_t)((b * 8 + kv) * 32) * 4096;
  const u16* btb = biasTT + (size_t)(h * 528 + qt * (qt + 1) / 2) * 1024;

  f32x16 o0, o1;
#pragma unroll
  for (int r = 0; r < 16; ++r) { o0[r] = 0.f; o1[r] = 0.f; }
  float lsum = 0.f;

  for (int it = w; it < nt; it += 4) {
    int t0 = it * 32;
    const char* Ksrc = Ktb + (size_t)it * 4096 + lane * 16;
    const char* Vsrc = Vtb + (size_t)it * 4096 + lane * 16;
    // issue K staging first, then V staging (vmcnt retires in order)
#pragma unroll
    for (int i = 0; i < 4; ++i) load_lds16(Ksrc + i * 1024, stg + i * 1024);
#pragma unroll
    for (int i = 0; i < 4; ++i) load_lds16(Vsrc + i * 1024, stg + 4096 + i * 1024);
    __builtin_amdgcn_sched_barrier(0);               // pin staging issue order
    asm volatile("s_waitcnt vmcnt(4)" ::: "memory"); // K complete; V still in flight
    __builtin_amdgcn_sched_barrier(0);
    // bias loads issue here; latency hides under QK MFMAs
    const u16* bl = btb + (size_t)it * 1024 + lane * 16;
    bf16x8 ba = *(const bf16x8*)bl;
    bf16x8 bb2 = *(const bf16x8*)(bl + 8);
    // S^T = K.Q^T
    f32x16 s;
#pragma unroll
    for (int r = 0; r < 16; ++r) s[r] = 0.f;
#pragma unroll
    for (int ks = 0; ks < 4; ++ks) {
      bf16x8 kc = *(const bf16x8*)(stg + ql * 128 + ((ks * 32 + hi * 16) ^ ((ql & 7) << 4)));
      s = __builtin_amdgcn_mfma_f32_32x32x16_bf16(kc, qf[ks], s, 0, 0, 0);
    }
    // bias add, mask, exp2 (m=0)
    bool diag = (it == nt - 1);
    float p[16];
    float ssum = 0.f;
#pragma unroll
    for (int r = 0; r < 16; ++r) {
      float sv = s[r] + (float)(r < 8 ? ba[r & 7] : bb2[r & 7]);
      if (diag) {
        int key = t0 + (r & 3) + 8 * (r >> 2) + 4 * hi;
        if (key > qg) sv = -1e30f;
      }
      float pe = exp2f(sv);
      p[r] = pe;
      ssum += pe;
    }
    lsum += ssum;
    // pack P -> bf16 pairs, redistribute across hi-split
    unsigned pk[8], tk[8];
#pragma unroll
    for (int j2 = 0; j2 < 8; ++j2) pk[j2] = pack_bf2(p[2 * j2], p[2 * j2 + 1]);
#pragma unroll
    for (int j2 = 0; j2 < 8; ++j2) tk[j2] = (unsigned)__shfl_xor((int)pk[j2], 32);
    union PU { unsigned u[4]; bf16x8 v; };
    PU pb0, pb1;
    pb0.u[0] = hi ? tk[2] : pk[0];
    pb0.u[1] = hi ? tk[3] : pk[1];
    pb0.u[2] = hi ? pk[2] : tk[0];
    pb0.u[3] = hi ? pk[3] : tk[1];
    pb1.u[0] = hi ? tk[6] : pk[4];
    pb1.u[1] = hi ? tk[7] : pk[5];
    pb1.u[2] = hi ? pk[6] : tk[4];
    pb1.u[3] = hi ? pk[7] : tk[5];
    // V staging complete before V LDS reads
    asm volatile("s_waitcnt vmcnt(0)" ::: "memory");
    __builtin_amdgcn_sched_barrier(0);
    char* Vl = stg + 4096;
    bf16x8 v00 = *(const bf16x8*)(Vl + ql * 128 + (((0 << 6) | (0 * 32 + hi * 16)) ^ ((ql & 7) << 4)));
    bf16x8 v01 = *(const bf16x8*)(Vl + ql * 128 + (((0 << 6) | (1 * 32 + hi * 16)) ^ ((ql & 7) << 4)));
    bf16x8 v10 = *(const bf16x8*)(Vl + ql * 128 + (((1 << 6) | (0 * 32 + hi * 16)) ^ ((ql & 7) << 4)));
    bf16x8 v11 = *(const bf16x8*)(Vl + ql * 128 + (((1 << 6) | (1 * 32 + hi * 16)) ^ ((ql & 7) << 4)));
    o0 = __builtin_amdgcn_mfma_f32_32x32x16_bf16(v00, pb0.v, o0, 0, 0, 0);
    o0 = __builtin_amdgcn_mfma_f32_32x32x16_bf16(v01, pb1.v, o0, 0, 0, 0);
    o1 = __builtin_amdgcn_mfma_f32_32x32x16_bf16(v10, pb0.v, o1, 0, 0, 0);
    o1 = __builtin_amdgcn_mfma_f32_32x32x16_bf16(v11, pb1.v, o1, 0, 0, 0);
  }

  // write partials (all share m=0 -> directly summable)
  lsum += __shfl_xor(lsum, 32);
  u16* Osh = (u16*)stg;
  float* Lsh = (float*)(smem + 32768);
#pragma unroll
  for (int r = 0; r < 16; ++r) {
    int row = (r & 3) + 8 * (r >> 2) + 4 * hi;
    Osh[row * 32 + ql]        = f2bf(o0[r]);
    Osh[(row + 32) * 32 + ql] = f2bf(o1[r]);
  }
  if (hi == 0) Lsh[w * 32 + ql] = lsum;
  __syncthreads();

  {
    int q = tid & 31, dg = tid >> 5;
    float* Lsh2 = (float*)(smem + 32768);
    float ltot = Lsh2[q] + Lsh2[32 + q] + Lsh2[64 + q] + Lsh2[96 + q];
    float invl = 1.0f / ltot;
    u16 ov[8];
#pragma unroll
    for (int j2 = 0; j2 < 8; ++j2) {
      int d = dg * 8 + j2;
      float acc = bf2f(*(u16*)(smem + 0 * 8192 + (d * 32 + q) * 2)) +
                  bf2f(*(u16*)(smem + 1 * 8192 + (d * 32 + q) * 2)) +
                  bf2f(*(u16*)(smem + 2 * 8192 + (d * 32 + q) * 2)) +
                  bf2f(*(u16*)(smem + 3 * 8192 + (d * 32 + q) * 2));
      ov[j2] = f2bf(acc * invl);
    }
    ushort4 out0, out1;
    out0.x = ov[0]; out0.y = ov[1]; out0.z = ov[2]; out0.w = ov[3];
    out1.x = ov[4]; out1.y = ov[5]; out1.z = ov[6]; out1.w = ov[7];
    u16* Yp = Yb + ((size_t)b * 1024 + qt * 32 + q) * 1024 + h * 64 + dg * 8;
    *(ushort4*)Yp = out0;
    *(ushort4*)(Yp + 4) = out1;
  }
}

extern "C" void kernel_launch(void* const* d_in, const int* in_sizes, int n_in,
                              void* d_out, int out_size, void* d_ws, size_t ws_size,
                              hipStream_t stream) {
  const float* x     = (const float*)d_in[0];
  const float* enc   = (const float*)d_in[1];
  const float* freqs = (const float*)d_in[2];
  const float* bias  = (const float*)d_in[3];
  const float* Wq    = (const float*)d_in[4];
  const float* Wk    = (const float*)d_in[5];
  const float* Wv    = (const float*)d_in[6];
  const float* Wo    = (const float*)d_in[7];
  const float* qs    = (const float*)d_in[8];
  const float* ks    = (const float*)d_in[9];

  char* ws = (char*)d_ws;
  size_t off = 0;
  auto alloc = [&](size_t bytes) { char* p = ws + off; off += (bytes + 255) & ~(size_t)255; return p; };
  u16*   xb     = (u16*)alloc(8388608);     // x bf16 (4096 x 1024)
  u16*   eb     = (u16*)alloc(8388608);     // enc bf16
  u16*   WqT    = (u16*)alloc(2097152);
  u16*   WkT    = (u16*)alloc(1048576);
  u16*   WvT    = (u16*)alloc(1048576);
  u16*   WoT    = (u16*)alloc(2097152);
  u16*   Qb     = (u16*)alloc(8388608);     // (B,H,T,D) bf16
  u16*   Ktiles = (u16*)alloc(4194304);     // 1024 tiles x 4 KB (swizzled)
  u16*   Vtiles = (u16*)alloc(4194304);     // 1024 tiles x 4 KB (swizzled)
  u16*   biasTT = (u16*)alloc(17301504);    // 16 x 528 causal tiles x 2 KB
  float* cstab  = (float*)alloc(131072);
  float* sntab  = (float*)alloc(131072);
  u16*   Yb     = (u16*)xb;                 // alias: xb dead after QKV GEMM

  prologue_kernel<<<6272, 256, 0, stream>>>(x, enc, freqs, Wq, Wk, Wv, Wo,
                                            xb, eb, WqT, WkT, WvT, WoT, cstab, sntab);

  gemm_qkv_kernel<<<dim3(32, 16, 3), 256, 0, stream>>>(xb, eb, WqT, WkT, WvT,
                                                       qs, ks, cstab, sntab, bias,
                                                       Qb, Ktiles, Vtiles, biasTT);

  attn_kernel<<<dim3(2048), 256, 0, stream>>>(Qb, Ktiles, Vtiles, biasTT, Yb);

  gemm_out_kernel<<<dim3(32, 16), 256, 0, stream>>>(Yb, WoT, (float*)d_out);
}